// Round 8
// baseline (395.052 us; speedup 1.0000x reference)
//
#include <hip/hip_runtime.h>
#include <cstdint>
#include <cstddef>

// Problem constants
#define M_DIM 8192
#define N_DIM 4096
#define K_DIM 4096

#define BM 256
#define BN 256
// K-tile = 128 bytes of K per row; 2 K-tiles per iteration; 4096/256 = 16 iters.

using i32x4 = __attribute__((ext_vector_type(4))) int;

__device__ __forceinline__ void async_load16(const void* g, void* l) {
    __builtin_amdgcn_global_load_lds(
        (const __attribute__((address_space(1))) void*)g,
        (__attribute__((address_space(3))) void*)l,
        16, 0, 0);
}

// Pack int32 values (range [-128,127]) to int8, both buffers in one launch.
__global__ __launch_bounds__(256) void pack_i8_kernel(const int4* __restrict__ xsrc,
                                                      int* __restrict__ xdst,
                                                      const int4* __restrict__ wsrc,
                                                      int* __restrict__ wdst,
                                                      int nxblocks) {
    const bool isw = (int)blockIdx.x >= nxblocks;
    const int4* src = isw ? wsrc : xsrc;
    int*       dst  = isw ? wdst : xdst;
    const long bb   = isw ? ((long)blockIdx.x - nxblocks) : (long)blockIdx.x;
    const long base = bb * 1024 + threadIdx.x;
#pragma unroll
    for (int j = 0; j < 4; ++j) {
        const long i = base + 256 * j;
        const int4 v = src[i];
        dst[i] = (v.x & 0xff) | ((v.y & 0xff) << 8) | ((v.z & 0xff) << 16) | (v.w << 24);
    }
}

// 256x256-tile 4-phase i8 GEMM. Phase-merged version of the verified 8-phase
// kernel: each phase computes TWO quadrants sharing one A-half (P1: (0,0)+(0,1)
// with af=Ah0; P2: (1,1)+(1,0) with af=Ah1, bf reused from registers).
// Rationale: measured ~700 cyc/phase fixed overhead (barriers/sync) vs ~650 cyc
// MFMA; halving phase count amortizes it over 2x the MFMA work.
// ds_read total unchanged (24 b128/wave/K-tile). Fragment, swizzle, staging and
// epilogue geometry byte-identical to the absmax-0 r5-r7 kernels.
// LDS map (128 KiB): A: buf*32768 + half*16384 + row*128; B: +65536.
// 16B chunks XOR-swizzled by (row&7) via pre-swizzled global source (rule 21).
__global__ __launch_bounds__(512, 2) void qgemm_i8_kernel(const int8_t* __restrict__ A,
                                                          const int8_t* __restrict__ B,
                                                          const int* __restrict__ bias,
                                                          const float* __restrict__ wscale,
                                                          int* __restrict__ C) {
    __shared__ int8_t LDS[131072];

    const int tid  = threadIdx.x;
    const int wave = tid >> 6;
    const int lane = tid & 63;
    const int wm = wave >> 2;   // 0..1
    const int wn = wave & 3;    // 0..3
    const int bm = blockIdx.y;
    const int bn = blockIdx.x;

    const int8_t* Ab = A + (size_t)bm * BM * K_DIM;
    const int8_t* Bb = B + (size_t)bn * BN * K_DIM;

    // Staging: per ISSUE_HT a wave covers 16 rows x 128B (2 x global_load_lds).
    // Lane l -> row +(l>>3), source chunk (l&7)^(l>>3) (pre-swizzled global).
    const int l8 = lane >> 3;
    const int l7 = lane & 7;
    const int8_t* Ag = Ab + (size_t)(wave * 16 + l8) * K_DIM + ((l7 ^ l8) * 16);
    const int8_t* Bg = Bb + (size_t)(wave * 16 + l8) * K_DIM + ((l7 ^ l8) * 16);
    const int sdst = wave * 2048;

    // Fragment ds_read bases. A row = mh*128 + wm*64 + mi*16 + (lane&15);
    // chunk = (kk*4 + (lane>>4)) ^ (row&7); row&7 == lane&7. kk=1 addr = kk=0 ^ 64.
    const int l15 = lane & 15;
    const int qh  = lane >> 4;
    const int a_off0 = wm * 8192 + l15 * 128 + ((qh ^ l7) * 16);
    const int a_off1 = a_off0 ^ 64;
    const int b_off0 = 65536 + wn * 4096 + l15 * 128 + ((qh ^ l7) * 16);
    const int b_off1 = b_off0 ^ 64;

    i32x4 acc[4][4][2] = {};   // [quadrant][mi][ni]
    i32x4 af[4][2];            // current A-half fragments
    i32x4 bf[2][2][2];         // BOTH B-half fragments [nh][ni][kk], held all K-tile

#define ISSUE_HT(GB, REG, BUF, HH, T) do { \
    async_load16((GB) + (size_t)((HH) * 128)     * K_DIM + (size_t)(T) * 128, \
                 &LDS[(REG) + (BUF) * 32768 + (HH) * 16384 + sdst]); \
    async_load16((GB) + (size_t)((HH) * 128 + 8) * K_DIM + (size_t)(T) * 128, \
                 &LDS[(REG) + (BUF) * 32768 + (HH) * 16384 + sdst + 1024]); \
} while (0)

#define LOAD_AF(BUF, MH) do { \
    _Pragma("unroll") \
    for (int mi = 0; mi < 4; ++mi) { \
        af[mi][0] = *(const i32x4*)&LDS[a_off0 + (BUF) * 32768 + (MH) * 16384 + mi * 2048]; \
        af[mi][1] = *(const i32x4*)&LDS[a_off1 + (BUF) * 32768 + (MH) * 16384 + mi * 2048]; \
    } \
} while (0)

#define LOAD_BF(BUF, NH) do { \
    _Pragma("unroll") \
    for (int ni = 0; ni < 2; ++ni) { \
        bf[NH][ni][0] = *(const i32x4*)&LDS[b_off0 + (BUF) * 32768 + (NH) * 16384 + ni * 2048]; \
        bf[NH][ni][1] = *(const i32x4*)&LDS[b_off1 + (BUF) * 32768 + (NH) * 16384 + ni * 2048]; \
    } \
} while (0)

#define VM8 asm volatile("s_waitcnt vmcnt(8)" ::: "memory")
#define VM4 asm volatile("s_waitcnt vmcnt(4)" ::: "memory")
#define VM0 asm volatile("s_waitcnt vmcnt(0)" ::: "memory")

// One phase: ds_reads, staging issues, vmcnt checkpoint (covers the loads the
// NEXT phase's ds_reads need, per the FIFO ledger), barrier, then 32 MFMA over
// two quadrants QDA (with bf[NA]) and QDB (with bf[NB]) sharing af.
#define PHASE2(LOADS, QDA, NA, QDB, NB, ISSUES, CHK) do { \
    LOADS; \
    ISSUES; \
    CHK; \
    __builtin_amdgcn_s_barrier(); \
    __builtin_amdgcn_s_setprio(1); \
    _Pragma("unroll") \
    for (int mi = 0; mi < 4; ++mi) { \
        _Pragma("unroll") \
        for (int ni = 0; ni < 2; ++ni) { \
            acc[QDA][mi][ni] = __builtin_amdgcn_mfma_i32_16x16x64_i8(af[mi][0], bf[NA][ni][0], acc[QDA][mi][ni], 0, 0, 0); \
            acc[QDA][mi][ni] = __builtin_amdgcn_mfma_i32_16x16x64_i8(af[mi][1], bf[NA][ni][1], acc[QDA][mi][ni], 0, 0, 0); \
        } \
    } \
    _Pragma("unroll") \
    for (int mi = 0; mi < 4; ++mi) { \
        _Pragma("unroll") \
        for (int ni = 0; ni < 2; ++ni) { \
            acc[QDB][mi][ni] = __builtin_amdgcn_mfma_i32_16x16x64_i8(af[mi][0], bf[NB][ni][0], acc[QDB][mi][ni], 0, 0, 0); \
            acc[QDB][mi][ni] = __builtin_amdgcn_mfma_i32_16x16x64_i8(af[mi][1], bf[NB][ni][1], acc[QDB][mi][ni], 0, 0, 0); \
        } \
    } \
    __builtin_amdgcn_s_setprio(0); \
    __builtin_amdgcn_s_barrier(); \
} while (0)

    // ---- prologue: tile0 fully (A0h0,B0h0,B0h1,A0h1) + tile1 partial (A1h0,B1h0).
    // B1h1/A1h1 of tile1 are issued at P1 of iter 0 (steady-state pattern).
    // VM6 forces the first 3 HT (= P1's read set: A0h0,B0h0,B0h1) landed.
    ISSUE_HT(Ag, 0,     0, 0, 0);   // #1 A0h0
    ISSUE_HT(Bg, 65536, 0, 0, 0);   // #2 B0h0
    ISSUE_HT(Bg, 65536, 0, 1, 0);   // #3 B0h1
    ISSUE_HT(Ag, 0,     0, 1, 0);   // #4 A0h1
    ISSUE_HT(Ag, 0,     1, 0, 1);   // #5 A1h0
    ISSUE_HT(Bg, 65536, 1, 0, 1);   // #6 B1h0
    asm volatile("s_waitcnt vmcnt(6)" ::: "memory");
    __builtin_amdgcn_s_barrier();

    // ---- main loop. Iter i: buf0 = tile 2i (P1,P2), buf1 = tile 2i+1 (P3,P4).
    // vmcnt ledger (CHK@p covers reads@p+1; all overwrites >=2 barriers after
    // the region's last ds_read):
    //   P1: VM8 -> prev-P3-issued landed (covers P2's Ah1 read)
    //   P2: VM4 -> prev-P4 + P1 landed (covers P3's Ah0/Bh0/Bh1 reads)
    //   P3: VM8 -> no-op (P4's Ah1(V) was P1-issued, already landed)
    //   P4: VM4 -> P2 + P3 landed (covers next-P1's Ah0/Bh0/Bh1 reads)
    for (int i = 0; i < 16; ++i) {
        const int V = 2 * i + 1;
        const int W = 2 * i + 2;   // -> buf0
        const int X = 2 * i + 3;   // -> buf1
        const bool more = (i < 15);

        PHASE2({ LOAD_AF(0, 0); LOAD_BF(0, 0); LOAD_BF(0, 1); }, 0, 0, 1, 1,
               { ISSUE_HT(Bg, 65536, 1, 1, V); ISSUE_HT(Ag, 0, 1, 1, V); },
               VM8);
        PHASE2({ LOAD_AF(0, 1); }, 2, 1, 3, 0,
               { if (more) { ISSUE_HT(Ag, 0, 0, 0, W); ISSUE_HT(Bg, 65536, 0, 0, W); } },
               { if (more) { VM4; } else { VM0; } });
        PHASE2({ LOAD_AF(1, 0); LOAD_BF(1, 0); LOAD_BF(1, 1); }, 0, 0, 1, 1,
               { if (more) { ISSUE_HT(Bg, 65536, 0, 1, W); ISSUE_HT(Ag, 0, 0, 1, W); } },
               { if (more) { VM8; } else { VM0; } });
        PHASE2({ LOAD_AF(1, 1); }, 2, 1, 3, 0,
               { if (more) { ISSUE_HT(Ag, 0, 1, 0, X); ISSUE_HT(Bg, 65536, 1, 0, X); } },
               { if (more) { VM4; } else { VM0; } });
    }

#undef PHASE2
#undef VM0
#undef VM4
#undef VM8
#undef LOAD_BF
#undef LOAD_AF
#undef ISSUE_HT

    // ---- epilogue. C/D layout (verified): col = lane&15, row = (lane>>4)*4 + reg.
    // Quad map: qd -> (mh, nh): 0=(0,0) 1=(0,1) 2=(1,1) 3=(1,0).
    const int col16 = lane & 15;
    const int rquad = (lane >> 4) * 4;
#pragma unroll
    for (int qd = 0; qd < 4; ++qd) {
        const int mh = qd >> 1;
        const int nh = (qd >> 1) ^ (qd & 1);
#pragma unroll
        for (int ni = 0; ni < 2; ++ni) {
            const int col = bn * BN + nh * 128 + wn * 32 + ni * 16 + col16;
            // match np ref arithmetic exactly: (0.05f * ws) / 0.1f, all f32
            float s = 0.05f * wscale[col];
            s = s / 0.1f;
            const float bz = (float)bias[col];
#pragma unroll
            for (int mi = 0; mi < 4; ++mi) {
                const int row0 = bm * BM + mh * 128 + wm * 64 + mi * 16 + rquad;
#pragma unroll
                for (int r = 0; r < 4; ++r) {
                    float v = ((float)acc[qd][mi][ni][r] + bz) * s;
                    v = rintf(v);                          // RTNE, matches np.round
                    v = fminf(fmaxf(v, -128.0f), 127.0f);
                    C[(size_t)(row0 + r) * N_DIM + col] = (int)v;
                }
            }
        }
    }
}

extern "C" void kernel_launch(void* const* d_in, const int* in_sizes, int n_in,
                              void* d_out, int out_size, void* d_ws, size_t ws_size,
                              hipStream_t stream) {
    const int*   x32    = (const int*)d_in[0];     // int8 values promoted to int32
    const int*   w32    = (const int*)d_in[1];
    const int*   bias   = (const int*)d_in[2];
    const float* wscale = (const float*)d_in[3];
    int*         out    = (int*)d_out;

    int8_t* xp = (int8_t*)d_ws;                         // 32 MiB packed x
    int8_t* wp = xp + (size_t)M_DIM * K_DIM;            // 16 MiB packed w

    {
        const int nxblocks = (int)((long)M_DIM * K_DIM / 4 / 1024);   // 8192
        const int nwblocks = (int)((long)N_DIM * K_DIM / 4 / 1024);   // 4096
        pack_i8_kernel<<<nxblocks + nwblocks, 256, 0, stream>>>(
            (const int4*)x32, (int*)xp, (const int4*)w32, (int*)wp, nxblocks);
    }

    dim3 grid(N_DIM / BN, M_DIM / BM);   // (16, 32)
    qgemm_i8_kernel<<<grid, 512, 0, stream>>>(xp, wp, bias, wscale, out);
}

// Round 9
// 389.071 us; speedup vs baseline: 1.0154x; 1.0154x over previous
//
#include <hip/hip_runtime.h>
#include <cstdint>
#include <cstddef>

// Problem constants
#define M_DIM 8192
#define N_DIM 4096
#define K_DIM 4096

#define BM 256
#define BN 256
// K-tile = 128 bytes of K per row; 2 K-tiles per iteration; 4096/256 = 16 iters.

using i32x4 = __attribute__((ext_vector_type(4))) int;

__device__ __forceinline__ void async_load16(const void* g, void* l) {
    __builtin_amdgcn_global_load_lds(
        (const __attribute__((address_space(1))) void*)g,
        (__attribute__((address_space(3))) void*)l,
        16, 0, 0);
}

// Pack int32 values (range [-128,127]) to int8, both buffers in one launch.
__global__ __launch_bounds__(256) void pack_i8_kernel(const int4* __restrict__ xsrc,
                                                      int* __restrict__ xdst,
                                                      const int4* __restrict__ wsrc,
                                                      int* __restrict__ wdst,
                                                      int nxblocks) {
    const bool isw = (int)blockIdx.x >= nxblocks;
    const int4* src = isw ? wsrc : xsrc;
    int*       dst  = isw ? wdst : xdst;
    const long bb   = isw ? ((long)blockIdx.x - nxblocks) : (long)blockIdx.x;
    const long base = bb * 1024 + threadIdx.x;
#pragma unroll
    for (int j = 0; j < 4; ++j) {
        const long i = base + 256 * j;
        const int4 v = src[i];
        dst[i] = (v.x & 0xff) | ((v.y & 0xff) << 8) | ((v.z & 0xff) << 16) | (v.w << 24);
    }
}

// 256x256-tile 8-phase i8 GEMM (r7 structure = best measured, 144 us).
// This round: (1) vmcnt checkpoints ONLY at P4/P8 (template-style; was every
// phase) -- full FIFO ledger re-derived and verified for the r7 issue schedule;
// (2) T1 bijective XCD-chunked blockIdx swizzle: each XCD gets 4 contiguous
// A-panels (4 MB = one L2) x all 16 B-panels.
// Gray-code quadrant order holds A-half + both B-halves in registers
// (24 ds_read_b128 per wave per K-tile, the floor for this wave-tiling).
// LDS map (128 KiB): A: buf*32768 + half*16384 + row*128; B: +65536.
// 16B chunks XOR-swizzled by (row&7) via pre-swizzled global source (rule 21).
__global__ __launch_bounds__(512, 2) void qgemm_i8_kernel(const int8_t* __restrict__ A,
                                                          const int8_t* __restrict__ B,
                                                          const int* __restrict__ bias,
                                                          const float* __restrict__ wscale,
                                                          int* __restrict__ C) {
    __shared__ int8_t LDS[131072];

    const int tid  = threadIdx.x;
    const int wave = tid >> 6;
    const int lane = tid & 63;
    const int wm = wave >> 2;   // 0..1
    const int wn = wave & 3;    // 0..3

    // T1: XCD-chunked swizzle. grid = (16,32) -> 512 blocks, 512%8==0.
    // lin%8 = XCD (dispatch round-robin); XCD r covers bm in [4r, 4r+4) x all bn.
    const int lin = (int)(blockIdx.y * 16 + blockIdx.x);
    const int swz = (lin & 7) * 64 + (lin >> 3);
    const int bm = swz >> 4;    // 0..31
    const int bn = swz & 15;    // 0..15

    const int8_t* Ab = A + (size_t)bm * BM * K_DIM;
    const int8_t* Bb = B + (size_t)bn * BN * K_DIM;

    // Staging: per ISSUE_HT a wave covers 16 rows x 128B (2 x global_load_lds).
    // Lane l -> row +(l>>3), source chunk (l&7)^(l>>3) (pre-swizzled global).
    const int l8 = lane >> 3;
    const int l7 = lane & 7;
    const int8_t* Ag = Ab + (size_t)(wave * 16 + l8) * K_DIM + ((l7 ^ l8) * 16);
    const int8_t* Bg = Bb + (size_t)(wave * 16 + l8) * K_DIM + ((l7 ^ l8) * 16);
    const int sdst = wave * 2048;

    // Fragment ds_read bases. A row = mh*128 + wm*64 + mi*16 + (lane&15);
    // chunk = (kk*4 + (lane>>4)) ^ (row&7); row&7 == lane&7. kk=1 addr = kk=0 ^ 64.
    const int l15 = lane & 15;
    const int qh  = lane >> 4;
    const int a_off0 = wm * 8192 + l15 * 128 + ((qh ^ l7) * 16);
    const int a_off1 = a_off0 ^ 64;
    const int b_off0 = 65536 + wn * 4096 + l15 * 128 + ((qh ^ l7) * 16);
    const int b_off1 = b_off0 ^ 64;

    i32x4 acc[4][4][2] = {};   // [quadrant][mi][ni]
    i32x4 af[4][2];            // current A-half fragments (held across phases)
    i32x4 bf[2][2][2];         // BOTH B-half fragments [nh][ni][kk], held all K-tile

#define ISSUE_HT(GB, REG, BUF, HH, T) do { \
    async_load16((GB) + (size_t)((HH) * 128)     * K_DIM + (size_t)(T) * 128, \
                 &LDS[(REG) + (BUF) * 32768 + (HH) * 16384 + sdst]); \
    async_load16((GB) + (size_t)((HH) * 128 + 8) * K_DIM + (size_t)(T) * 128, \
                 &LDS[(REG) + (BUF) * 32768 + (HH) * 16384 + sdst + 1024]); \
} while (0)

#define LOAD_AF(BUF, MH) do { \
    _Pragma("unroll") \
    for (int mi = 0; mi < 4; ++mi) { \
        af[mi][0] = *(const i32x4*)&LDS[a_off0 + (BUF) * 32768 + (MH) * 16384 + mi * 2048]; \
        af[mi][1] = *(const i32x4*)&LDS[a_off1 + (BUF) * 32768 + (MH) * 16384 + mi * 2048]; \
    } \
} while (0)

#define LOAD_BF(BUF, NH) do { \
    _Pragma("unroll") \
    for (int ni = 0; ni < 2; ++ni) { \
        bf[NH][ni][0] = *(const i32x4*)&LDS[b_off0 + (BUF) * 32768 + (NH) * 16384 + ni * 2048]; \
        bf[NH][ni][1] = *(const i32x4*)&LDS[b_off1 + (BUF) * 32768 + (NH) * 16384 + ni * 2048]; \
    } \
} while (0)

#define VM6 asm volatile("s_waitcnt vmcnt(6)" ::: "memory")
#define VM0 asm volatile("s_waitcnt vmcnt(0)" ::: "memory")

#define PHASE(LOADS, QD, NHB, ISSUES, CHK) do { \
    LOADS; \
    ISSUES; \
    CHK; \
    __builtin_amdgcn_s_barrier(); \
    __builtin_amdgcn_s_setprio(1); \
    _Pragma("unroll") \
    for (int mi = 0; mi < 4; ++mi) { \
        _Pragma("unroll") \
        for (int ni = 0; ni < 2; ++ni) { \
            acc[QD][mi][ni] = __builtin_amdgcn_mfma_i32_16x16x64_i8(af[mi][0], bf[NHB][ni][0], acc[QD][mi][ni], 0, 0, 0); \
            acc[QD][mi][ni] = __builtin_amdgcn_mfma_i32_16x16x64_i8(af[mi][1], bf[NHB][ni][1], acc[QD][mi][ni], 0, 0, 0); \
        } \
    } \
    __builtin_amdgcn_s_setprio(0); \
    __builtin_amdgcn_s_barrier(); \
} while (0)

    // ---- prologue: tile0 fully + tile1 partial (A1h0, B1h1, A1h1).
    // B1h0(t1) is issued at P1 of iter 0. VM6 drains HT1-4 (= A0h0,B0h0,B0h1,
    // A0h1), covering all buf0 reads at P1-P3.
    ISSUE_HT(Ag, 0,     0, 0, 0);   // #1 A0h0
    ISSUE_HT(Bg, 65536, 0, 0, 0);   // #2 B0h0
    ISSUE_HT(Bg, 65536, 0, 1, 0);   // #3 B0h1
    ISSUE_HT(Ag, 0,     0, 1, 0);   // #4 A0h1
    ISSUE_HT(Ag, 0,     1, 0, 1);   // #5 A1h0
    ISSUE_HT(Bg, 65536, 1, 1, 1);   // #6 B1h1
    ISSUE_HT(Ag, 0,     1, 1, 1);   // #7 A1h1
    VM6;
    __builtin_amdgcn_s_barrier();

    // ---- main loop. Iter i: tiles U=2i (buf0, P1-4), V=2i+1 (buf1, P5-8).
    // Quadrants: P1=(0,0) P2=(0,1) P3=(1,1) P4=(1,0); loads only the changed half;
    // P4/P8 reuse B-half-0 registers from P1/P5 (no ds_read).
    // vmcnt ledger (checkpoints at P4/P8 only, per-wave FIFO, 2 loads/phase):
    //  P4's VM6 drains {prevP6,prevP7,prevP8,P1} -> covers P5(A1h0 prevP6,
    //    B1h0 P1), P6(B1h1 prevP7), P7(A1h1 prevP8).
    //  P8's VM6 drains {P2,P3,P4,P5} -> covers nextP1(A0h0 P2, B0h0 P5),
    //    nextP2(B0h1 P3), nextP3(A0h1 P4).
    //  Overwrite issues remain >=2 barriers after the region's last ds_read.
    //  Last iter: VM0 at P4 (covers P1-issued B1h0) and P8 (drain).
    for (int i = 0; i < 16; ++i) {
        const int V = 2 * i + 1;
        const int W = 2 * i + 2;   // -> buf0
        const int X = 2 * i + 3;   // -> buf1
        const bool more = (i < 15);

        PHASE({ LOAD_AF(0, 0); LOAD_BF(0, 0); }, 0, 0,
              { ISSUE_HT(Bg, 65536, 1, 0, V); }, {});
        PHASE({ LOAD_BF(0, 1); }, 1, 1,
              { if (more) ISSUE_HT(Ag, 0,     0, 0, W); }, {});
        PHASE({ LOAD_AF(0, 1); }, 2, 1,
              { if (more) ISSUE_HT(Bg, 65536, 0, 1, W); }, {});
        PHASE({}, 3, 0,
              { if (more) ISSUE_HT(Ag, 0,     0, 1, W); },
              { if (more) { VM6; } else { VM0; } });
        PHASE({ LOAD_AF(1, 0); LOAD_BF(1, 0); }, 0, 0,
              { if (more) ISSUE_HT(Bg, 65536, 0, 0, W); }, {});
        PHASE({ LOAD_BF(1, 1); }, 1, 1,
              { if (more) ISSUE_HT(Ag, 0,     1, 0, X); }, {});
        PHASE({ LOAD_AF(1, 1); }, 2, 1,
              { if (more) ISSUE_HT(Bg, 65536, 1, 1, X); }, {});
        PHASE({}, 3, 0,
              { if (more) ISSUE_HT(Ag, 0,     1, 1, X); },
              { if (more) { VM6; } else { VM0; } });
    }

#undef PHASE
#undef VM0
#undef VM6
#undef LOAD_BF
#undef LOAD_AF
#undef ISSUE_HT

    // ---- epilogue. C/D layout (verified): col = lane&15, row = (lane>>4)*4 + reg.
    // Quad map: qd -> (mh, nh): 0=(0,0) 1=(0,1) 2=(1,1) 3=(1,0).
    const int col16 = lane & 15;
    const int rquad = (lane >> 4) * 4;
#pragma unroll
    for (int qd = 0; qd < 4; ++qd) {
        const int mh = qd >> 1;
        const int nh = (qd >> 1) ^ (qd & 1);
#pragma unroll
        for (int ni = 0; ni < 2; ++ni) {
            const int col = bn * BN + nh * 128 + wn * 32 + ni * 16 + col16;
            // match np ref arithmetic exactly: (0.05f * ws) / 0.1f, all f32
            float s = 0.05f * wscale[col];
            s = s / 0.1f;
            const float bz = (float)bias[col];
#pragma unroll
            for (int mi = 0; mi < 4; ++mi) {
                const int row0 = bm * BM + mh * 128 + wm * 64 + mi * 16 + rquad;
#pragma unroll
                for (int r = 0; r < 4; ++r) {
                    float v = ((float)acc[qd][mi][ni][r] + bz) * s;
                    v = rintf(v);                          // RTNE, matches np.round
                    v = fminf(fmaxf(v, -128.0f), 127.0f);
                    C[(size_t)(row0 + r) * N_DIM + col] = (int)v;
                }
            }
        }
    }
}

extern "C" void kernel_launch(void* const* d_in, const int* in_sizes, int n_in,
                              void* d_out, int out_size, void* d_ws, size_t ws_size,
                              hipStream_t stream) {
    const int*   x32    = (const int*)d_in[0];     // int8 values promoted to int32
    const int*   w32    = (const int*)d_in[1];
    const int*   bias   = (const int*)d_in[2];
    const float* wscale = (const float*)d_in[3];
    int*         out    = (int*)d_out;

    int8_t* xp = (int8_t*)d_ws;                         // 32 MiB packed x
    int8_t* wp = xp + (size_t)M_DIM * K_DIM;            // 16 MiB packed w

    {
        const int nxblocks = (int)((long)M_DIM * K_DIM / 4 / 1024);   // 8192
        const int nwblocks = (int)((long)N_DIM * K_DIM / 4 / 1024);   // 4096
        pack_i8_kernel<<<nxblocks + nwblocks, 256, 0, stream>>>(
            (const int4*)x32, (int*)xp, (const int4*)w32, (int*)wp, nxblocks);
    }

    dim3 grid(N_DIM / BN, M_DIM / BM);   // (16, 32)
    qgemm_i8_kernel<<<grid, 512, 0, stream>>>(xp, wp, bias, wscale, out);
}

// Round 10
// 375.552 us; speedup vs baseline: 1.0519x; 1.0360x over previous
//
#include <hip/hip_runtime.h>
#include <cstdint>
#include <cstddef>

// Problem constants
#define M_DIM 8192
#define N_DIM 4096
#define K_DIM 4096

#define BM 256
#define BN 256
// K-tile = 128 bytes of K per row; 2 K-tiles per iteration; 4096/256 = 16 iters.

using i32x4 = __attribute__((ext_vector_type(4))) int;

__device__ __forceinline__ void async_load16(const void* g, void* l) {
    __builtin_amdgcn_global_load_lds(
        (const __attribute__((address_space(1))) void*)g,
        (__attribute__((address_space(3))) void*)l,
        16, 0, 0);
}

// Pack int32 values (range [-128,127]) to int8, both buffers in one launch.
__global__ __launch_bounds__(256) void pack_i8_kernel(const int4* __restrict__ xsrc,
                                                      int* __restrict__ xdst,
                                                      const int4* __restrict__ wsrc,
                                                      int* __restrict__ wdst,
                                                      int nxblocks) {
    const bool isw = (int)blockIdx.x >= nxblocks;
    const int4* src = isw ? wsrc : xsrc;
    int*       dst  = isw ? wdst : xdst;
    const long bb   = isw ? ((long)blockIdx.x - nxblocks) : (long)blockIdx.x;
    const long base = bb * 1024 + threadIdx.x;
#pragma unroll
    for (int j = 0; j < 4; ++j) {
        const long i = base + 256 * j;
        const int4 v = src[i];
        dst[i] = (v.x & 0xff) | ((v.y & 0xff) << 8) | ((v.z & 0xff) << 16) | (v.w << 24);
    }
}

// 256x256-tile 8-phase i8 GEMM, SINGLE barrier per phase (was 2).
// A wave finishing MFMA(p) proceeds straight into LOADS/ISSUES(p+1); the only
// sync point is the barrier before each MFMA cluster. Overwrite safety under
// one barrier requires issue-phase >= last-read-phase + 2, so the staging
// schedule is shifted vs r9: P1:A1h1(V) P3:A0h0,B0h0(W) P4:B0h1(W) P5:A0h1(W)
// P7:A1h0,B1h0(X) P8:B1h1(X). vmcnt(6) checkpoints at P4/P8 only (FIFO ledger:
// P4 drains prevP7/prevP8/P1 covering P5-P7 reads; P8 drains P3/P4/P5 covering
// next P1-P3 reads). Gray-code quadrants hold A-half + both B-halves in regs
// (24 ds_read_b128/wave/K-tile). T1 XCD-chunked block swizzle.
// LDS map (128 KiB): A: buf*32768 + half*16384 + row*128; B: +65536.
// 16B chunks XOR-swizzled by (row&7) via pre-swizzled global source (rule 21).
__global__ __launch_bounds__(512, 2) void qgemm_i8_kernel(const int8_t* __restrict__ A,
                                                          const int8_t* __restrict__ B,
                                                          const int* __restrict__ bias,
                                                          const float* __restrict__ wscale,
                                                          int* __restrict__ C) {
    __shared__ int8_t LDS[131072];

    const int tid  = threadIdx.x;
    const int wave = tid >> 6;
    const int lane = tid & 63;
    const int wm = wave >> 2;   // 0..1
    const int wn = wave & 3;    // 0..3

    // T1: XCD-chunked swizzle. grid = (16,32) -> 512 blocks, 512%8==0.
    // lin%8 = XCD (dispatch round-robin); XCD r covers bm in [4r, 4r+4) x all bn.
    const int lin = (int)(blockIdx.y * 16 + blockIdx.x);
    const int swz = (lin & 7) * 64 + (lin >> 3);
    const int bm = swz >> 4;    // 0..31
    const int bn = swz & 15;    // 0..15

    const int8_t* Ab = A + (size_t)bm * BM * K_DIM;
    const int8_t* Bb = B + (size_t)bn * BN * K_DIM;

    // Staging: per ISSUE_HT a wave covers 16 rows x 128B (2 x global_load_lds).
    // Lane l -> row +(l>>3), source chunk (l&7)^(l>>3) (pre-swizzled global).
    const int l8 = lane >> 3;
    const int l7 = lane & 7;
    const int8_t* Ag = Ab + (size_t)(wave * 16 + l8) * K_DIM + ((l7 ^ l8) * 16);
    const int8_t* Bg = Bb + (size_t)(wave * 16 + l8) * K_DIM + ((l7 ^ l8) * 16);
    const int sdst = wave * 2048;

    // Fragment ds_read bases. A row = mh*128 + wm*64 + mi*16 + (lane&15);
    // chunk = (kk*4 + (lane>>4)) ^ (row&7); row&7 == lane&7. kk=1 addr = kk=0 ^ 64.
    const int l15 = lane & 15;
    const int qh  = lane >> 4;
    const int a_off0 = wm * 8192 + l15 * 128 + ((qh ^ l7) * 16);
    const int a_off1 = a_off0 ^ 64;
    const int b_off0 = 65536 + wn * 4096 + l15 * 128 + ((qh ^ l7) * 16);
    const int b_off1 = b_off0 ^ 64;

    i32x4 acc[4][4][2] = {};   // [quadrant][mi][ni]
    i32x4 af[4][2];            // current A-half fragments (held across phases)
    i32x4 bf[2][2][2];         // BOTH B-half fragments [nh][ni][kk], held all K-tile

#define ISSUE_HT(GB, REG, BUF, HH, T) do { \
    async_load16((GB) + (size_t)((HH) * 128)     * K_DIM + (size_t)(T) * 128, \
                 &LDS[(REG) + (BUF) * 32768 + (HH) * 16384 + sdst]); \
    async_load16((GB) + (size_t)((HH) * 128 + 8) * K_DIM + (size_t)(T) * 128, \
                 &LDS[(REG) + (BUF) * 32768 + (HH) * 16384 + sdst + 1024]); \
} while (0)

#define LOAD_AF(BUF, MH) do { \
    _Pragma("unroll") \
    for (int mi = 0; mi < 4; ++mi) { \
        af[mi][0] = *(const i32x4*)&LDS[a_off0 + (BUF) * 32768 + (MH) * 16384 + mi * 2048]; \
        af[mi][1] = *(const i32x4*)&LDS[a_off1 + (BUF) * 32768 + (MH) * 16384 + mi * 2048]; \
    } \
} while (0)

#define LOAD_BF(BUF, NH) do { \
    _Pragma("unroll") \
    for (int ni = 0; ni < 2; ++ni) { \
        bf[NH][ni][0] = *(const i32x4*)&LDS[b_off0 + (BUF) * 32768 + (NH) * 16384 + ni * 2048]; \
        bf[NH][ni][1] = *(const i32x4*)&LDS[b_off1 + (BUF) * 32768 + (NH) * 16384 + ni * 2048]; \
    } \
} while (0)

#define VM6 asm volatile("s_waitcnt vmcnt(6)" ::: "memory")
#define VM0 asm volatile("s_waitcnt vmcnt(0)" ::: "memory")

// One phase: ds_reads + staging issues + optional vmcnt checkpoint, ONE
// barrier, then the 16-MFMA quadrant cluster. No closing barrier: the wave
// rolls straight into the next phase's loads, overlapping other waves' MFMA.
#define PHASE(LOADS, QD, NHB, ISSUES, CHK) do { \
    LOADS; \
    ISSUES; \
    CHK; \
    __builtin_amdgcn_s_barrier(); \
    __builtin_amdgcn_s_setprio(1); \
    _Pragma("unroll") \
    for (int mi = 0; mi < 4; ++mi) { \
        _Pragma("unroll") \
        for (int ni = 0; ni < 2; ++ni) { \
            acc[QD][mi][ni] = __builtin_amdgcn_mfma_i32_16x16x64_i8(af[mi][0], bf[NHB][ni][0], acc[QD][mi][ni], 0, 0, 0); \
            acc[QD][mi][ni] = __builtin_amdgcn_mfma_i32_16x16x64_i8(af[mi][1], bf[NHB][ni][1], acc[QD][mi][ni], 0, 0, 0); \
        } \
    } \
    __builtin_amdgcn_s_setprio(0); \
} while (0)

    // ---- prologue: tile0 fully + tile1 partial (A1h0, B1h0, B1h1).
    // A1h1(t1) is issued at P1 of iter 0. vmcnt(6) drains HT1-4 (all buf0),
    // covering P1-P3 reads.
    ISSUE_HT(Ag, 0,     0, 0, 0);   // #1 A0h0
    ISSUE_HT(Bg, 65536, 0, 0, 0);   // #2 B0h0
    ISSUE_HT(Bg, 65536, 0, 1, 0);   // #3 B0h1
    ISSUE_HT(Ag, 0,     0, 1, 0);   // #4 A0h1
    ISSUE_HT(Ag, 0,     1, 0, 1);   // #5 A1h0
    ISSUE_HT(Bg, 65536, 1, 0, 1);   // #6 B1h0
    ISSUE_HT(Bg, 65536, 1, 1, 1);   // #7 B1h1
    VM6;
    __builtin_amdgcn_s_barrier();

    // ---- main loop. Iter i: tiles U=2i (buf0, P1-4), V=2i+1 (buf1, P5-8).
    // Quadrants: P1=(0,0) P2=(0,1) P3=(1,1) P4=(1,0).
    // Overwrite ledger (single-barrier rule: issue >= last-read + 2):
    //   buf0 Ah0/Bh0 read P1 -> issued P3; Bh1 read P2 -> P4; Ah1 read P3 -> P5
    //   buf1 Ah0/Bh0 read P5 -> issued P7; Bh1 read P6 -> P8; Ah1 read P7 -> next P1
    // Landing ledger: VM6@P4 drains prevP7+prevP8+P1 (covers P5-P7 reads);
    //   VM6@P8 drains P3+P4+P5 (covers next P1-P3 reads). Last iter: VM0@P4.
    for (int i = 0; i < 16; ++i) {
        const int V = 2 * i + 1;
        const int W = 2 * i + 2;   // -> buf0
        const int X = 2 * i + 3;   // -> buf1
        const bool more = (i < 15);

        PHASE({ LOAD_AF(0, 0); LOAD_BF(0, 0); }, 0, 0,
              { ISSUE_HT(Ag, 0,     1, 1, V); }, {});
        PHASE({ LOAD_BF(0, 1); }, 1, 1,
              {}, {});
        PHASE({ LOAD_AF(0, 1); }, 2, 1,
              { if (more) { ISSUE_HT(Ag, 0, 0, 0, W); ISSUE_HT(Bg, 65536, 0, 0, W); } }, {});
        PHASE({}, 3, 0,
              { if (more) ISSUE_HT(Bg, 65536, 0, 1, W); },
              { if (more) { VM6; } else { VM0; } });
        PHASE({ LOAD_AF(1, 0); LOAD_BF(1, 0); }, 0, 0,
              { if (more) ISSUE_HT(Ag, 0,     0, 1, W); }, {});
        PHASE({ LOAD_BF(1, 1); }, 1, 1,
              {}, {});
        PHASE({ LOAD_AF(1, 1); }, 2, 1,
              { if (more) { ISSUE_HT(Ag, 0, 1, 0, X); ISSUE_HT(Bg, 65536, 1, 0, X); } }, {});
        PHASE({}, 3, 0,
              { if (more) ISSUE_HT(Bg, 65536, 1, 1, X); },
              { if (more) { VM6; } });
    }

#undef PHASE
#undef VM0
#undef VM6
#undef LOAD_BF
#undef LOAD_AF
#undef ISSUE_HT

    // ---- epilogue. C/D layout (verified): col = lane&15, row = (lane>>4)*4 + reg.
    // Quad map: qd -> (mh, nh): 0=(0,0) 1=(0,1) 2=(1,1) 3=(1,0).
    const int col16 = lane & 15;
    const int rquad = (lane >> 4) * 4;
#pragma unroll
    for (int qd = 0; qd < 4; ++qd) {
        const int mh = qd >> 1;
        const int nh = (qd >> 1) ^ (qd & 1);
#pragma unroll
        for (int ni = 0; ni < 2; ++ni) {
            const int col = bn * BN + nh * 128 + wn * 32 + ni * 16 + col16;
            // match np ref arithmetic exactly: (0.05f * ws) / 0.1f, all f32
            float s = 0.05f * wscale[col];
            s = s / 0.1f;
            const float bz = (float)bias[col];
#pragma unroll
            for (int mi = 0; mi < 4; ++mi) {
                const int row0 = bm * BM + mh * 128 + wm * 64 + mi * 16 + rquad;
#pragma unroll
                for (int r = 0; r < 4; ++r) {
                    float v = ((float)acc[qd][mi][ni][r] + bz) * s;
                    v = rintf(v);                          // RTNE, matches np.round
                    v = fminf(fmaxf(v, -128.0f), 127.0f);
                    C[(size_t)(row0 + r) * N_DIM + col] = (int)v;
                }
            }
        }
    }
}

extern "C" void kernel_launch(void* const* d_in, const int* in_sizes, int n_in,
                              void* d_out, int out_size, void* d_ws, size_t ws_size,
                              hipStream_t stream) {
    const int*   x32    = (const int*)d_in[0];     // int8 values promoted to int32
    const int*   w32    = (const int*)d_in[1];
    const int*   bias   = (const int*)d_in[2];
    const float* wscale = (const float*)d_in[3];
    int*         out    = (int*)d_out;

    int8_t* xp = (int8_t*)d_ws;                         // 32 MiB packed x
    int8_t* wp = xp + (size_t)M_DIM * K_DIM;            // 16 MiB packed w

    {
        const int nxblocks = (int)((long)M_DIM * K_DIM / 4 / 1024);   // 8192
        const int nwblocks = (int)((long)N_DIM * K_DIM / 4 / 1024);   // 4096
        pack_i8_kernel<<<nxblocks + nwblocks, 256, 0, stream>>>(
            (const int4*)x32, (int*)xp, (const int4*)w32, (int*)wp, nxblocks);
    }

    dim3 grid(N_DIM / BN, M_DIM / BM);   // (16, 32)
    qgemm_i8_kernel<<<grid, 512, 0, stream>>>(xp, wp, bias, wscale, out);
}